// Round 6
// baseline (369.713 us; speedup 1.0000x reference)
//
#include <hip/hip_runtime.h>
#include <hip/hip_bf16.h>
#include <math.h>

#define N_TOK 2048
#define H_DIM 1024
#define N_EXP 16
#define I_DIM 768
#define TOPK 4
#define SCALE 2.5f

// XCD-aware work tables: slot F -> XCD F%8 (dispatch round-robin).
// Tiles sharing a weight panel (same expert+N-slice) get the same residue mod 8.
#define GU_SLOTS 256
#define DN_SLOTS 192
#define GU_TAB (8 * GU_SLOTS)   // 2048
#define DN_TAB (8 * DN_SLOTS)   // 1536
#define GU_NY (I_DIM / 64)      // 12
#define DN_NY (H_DIM / 128)     // 8
#define MAX_GRP 832

typedef __attribute__((ext_vector_type(8))) short bf16x8;
typedef __attribute__((ext_vector_type(4))) float f32x4;

// workspace layout (bytes)
#define OFF_COUNTS   0
#define OFF_OFFSETS  128
#define OFF_WGU      256
#define OFF_WDN      (OFF_WGU + GU_TAB*4)
#define OFF_TOKIDS   (OFF_WDN + DN_TAB*4)
#define OFF_TOKW     (OFF_TOKIDS + N_EXP*N_TOK*4)
#define OFF_XB       (OFF_TOKW + N_EXP*N_TOK*4)
#define OFF_HACT     (OFF_XB + (size_t)N_TOK*H_DIM*2)
#define OFF_GWT      (OFF_HACT + (size_t)N_TOK*(TOPK+1)*I_DIM*2)
// total ~20 MB

__device__ __forceinline__ ushort f2bf(float f) {
    union { __hip_bfloat16 h; ushort u; } cv;
    cv.h = __float2bfloat16(f);
    return cv.u;
}
__device__ __forceinline__ unsigned pack2(float lo, float hi) {
    return (unsigned)f2bf(lo) | ((unsigned)f2bf(hi) << 16);
}
__device__ __forceinline__ void async_copy16(const void* g, void* l) {
    __builtin_amdgcn_global_load_lds(
        (const __attribute__((address_space(1))) unsigned int*)g,
        (__attribute__((address_space(3))) unsigned int*)l, 16, 0, 0);
}

// ---------------- gate_w transpose: gwT[k][e] ----------------
__global__ void k_gwt(const float* __restrict__ gw, float* __restrict__ gwT) {
    int i = blockIdx.x * 256 + threadIdx.x;   // 16384 elements
    int k = i >> 4, e = i & 15;
    gwT[i] = gw[e * H_DIM + k];
}

// ---------------- routing: 1 wave/token, lane = (kslice, expert) ----------------
// Also emits xb (bf16 x) from its e==0 lanes — replaces the separate k_xconv.
__launch_bounds__(256)
__global__ void k_route(const float* __restrict__ x, const float* __restrict__ gwT,
                        const float* __restrict__ gb,
                        int* __restrict__ counts, int* __restrict__ tok_ids,
                        float* __restrict__ tok_w, ushort* __restrict__ xb) {
    __shared__ float lgs[4][N_EXP + 1];
    int tid = threadIdx.x;
    int wv = tid >> 6, lane = tid & 63;
    int e = lane & 15, ks = lane >> 4;
    int n = blockIdx.x * 4 + wv;

    const float* xr = x + (size_t)n * H_DIM + ks * 256;
    ushort* xbr = xb + (size_t)n * H_DIM + ks * 256;
    const float* wr = gwT + ks * 256 * N_EXP + e;
    float a0 = 0.f, a1 = 0.f, a2 = 0.f, a3 = 0.f;
#pragma unroll 8
    for (int k = 0; k < 256; k += 4) {
        float4 xv = *(const float4*)(xr + k);
        a0 += xv.x * wr[(k + 0) * N_EXP];
        a1 += xv.y * wr[(k + 1) * N_EXP];
        a2 += xv.z * wr[(k + 2) * N_EXP];
        a3 += xv.w * wr[(k + 3) * N_EXP];
        if (e == 0) {   // bf16 copy of x (each 4-float chunk written once)
            uint2 p;
            p.x = pack2(xv.x, xv.y);
            p.y = pack2(xv.z, xv.w);
            *(uint2*)(xbr + k) = p;
        }
    }
    float acc = (a0 + a1) + (a2 + a3);
    acc += __shfl_xor(acc, 16);
    acc += __shfl_xor(acc, 32);
    if (lane < 16) lgs[wv][lane] = acc;
    __syncthreads();

    if (tid < 4) {
        int n2 = blockIdx.x * 4 + tid;
        float sc[N_EXP], sb[N_EXP];
        for (int ee = 0; ee < N_EXP; ee++) {
            float l = lgs[tid][ee];
            sc[ee] = 1.f / (1.f + expf(-l));
            sb[ee] = sc[ee] + gb[ee];
        }
        float gsc[4];
        for (int g = 0; g < 4; g++) {
            float m1 = -1e30f, m2 = -1e30f;
            for (int j = 0; j < 4; j++) {
                float v = sb[4 * g + j];
                if (v > m1) { m2 = m1; m1 = v; }
                else if (v > m2) m2 = v;
            }
            gsc[g] = m1 + m2;
        }
        int g1 = 0;
        for (int g = 1; g < 4; g++) if (gsc[g] > gsc[g1]) g1 = g;
        int g2 = -1;
        for (int g = 0; g < 4; g++) {
            if (g == g1) continue;
            if (g2 < 0 || gsc[g] > gsc[g2]) g2 = g;
        }
        bool allowed[N_EXP];
        for (int ee = 0; ee < N_EXP; ee++) {
            int grp = ee >> 2;
            allowed[ee] = (grp == g1) || (grp == g2);
        }
        int chosen[TOPK];
        float wsum = 0.f;
        for (int k = 0; k < TOPK; k++) {
            int best = -1;
            for (int ee = 0; ee < N_EXP; ee++) {
                if (!allowed[ee]) continue;
                if (best < 0 || sb[ee] > sb[best]) best = ee;
            }
            chosen[k] = best;
            allowed[best] = false;
            wsum += sc[best];
        }
        float inv = SCALE / (wsum + 1e-20f);
        for (int k = 0; k < TOPK; k++) {
            int ee = chosen[k];
            int p = atomicAdd(&counts[ee], 1);
            tok_ids[ee * N_TOK + p] = n2;
            tok_w[ee * N_TOK + p] = sc[ee] * inv;
        }
    }
}

// ---------------- scan + XCD-aware work tables (fully parallel build) ----------------
// Group = <=4 m-tiles sharing one weight panel (same e, same N-slice).
// Groups enumerated (e, y, mchunk); group id g -> XCD g%8 (within its table).
// Closed-form: gpe[e]=ceil(nmt/4) groups per y -> expert base by 17-elem prefix.
// desc = e | (m << 5) | (y << 9)
__global__ void k_scan(const int* __restrict__ counts, int* __restrict__ offsets,
                       int* __restrict__ wgu, int* __restrict__ wdn) {
    __shared__ int nmt_s[20], gpe_s[20];
    __shared__ int geb[20], deb[20];
    __shared__ int gmeta[MAX_GRP];   // e | m0<<5 | y<<9 | size<<24
    __shared__ int gslot[MAX_GRP];
    __shared__ int ngu_s, ntot_s;
    int tid = threadIdx.x;
    for (int i = tid; i < GU_TAB; i += 256) wgu[i] = -1;
    for (int i = tid; i < DN_TAB; i += 256) wdn[i] = -1;
    if (tid < 17) {
        int c = (tid == 16) ? N_TOK : counts[tid];
        int nm = (c + 127) >> 7;
        nmt_s[tid] = nm;
        gpe_s[tid] = (nm + 3) >> 2;
    }
    __syncthreads();
    if (tid == 0) {
        int off = 0;
        for (int e = 0; e < N_EXP; e++) { offsets[e] = off; off += counts[e]; }
        offsets[N_EXP] = off;   // shared expert base (= 8192)
        int g = 0, d = 0;
        for (int e = 0; e <= N_EXP; e++) {
            geb[e] = g; g += GU_NY * gpe_s[e];
            deb[e] = d; d += DN_NY * gpe_s[e];
        }
        geb[N_EXP + 1] = g; deb[N_EXP + 1] = d;
        ngu_s = g; ntot_s = g + d;
    }
    __syncthreads();
    int ngu = ngu_s, ntot = ntot_s;
    // group metadata, parallel over groups
    for (int g = tid; g < ntot; g += 256) {
        bool gu = g < ngu;
        int r = gu ? g : g - ngu;
        const int* eb = gu ? geb : deb;
        int e = 0;
        while (eb[e + 1] <= r) e++;
        int rem = r - eb[e];
        int gp = gpe_s[e];
        int y = rem / gp, mc = rem - y * gp;
        int m0t = mc * 4;
        int size = nmt_s[e] - m0t; if (size > 4) size = 4;
        gmeta[g] = e | (m0t << 5) | (y << 9) | (size << 24);
    }
    __syncthreads();
    // per-XCD slot prefix: 8 threads for GU, 8 for DN; strided, branch-free
    if (tid < 8) {
        int s = 0;
        for (int g = tid; g < ngu; g += 8) { gslot[g] = s; s += (gmeta[g] >> 24); }
    } else if (tid < 16) {
        int c = tid - 8, s = 0;
        for (int g = ngu + c; g < ntot; g += 8) { gslot[g] = s; s += (gmeta[g] >> 24); }
    }
    __syncthreads();
    // expand groups -> tables (tile k of group g at slot gslot[g]+k on XCD r%8)
    int k = tid & 3;
    for (int g = tid >> 2; g < ntot; g += 64) {
        int p = gmeta[g];
        int size = (p >> 24);
        if (k >= size) continue;
        int desc = (p & 0x1FFF) + (k << 5);
        bool gu = g < ngu;
        int r = gu ? g : g - ngu;
        int idx = (r & 7) + 8 * (gslot[g] + k);
        if (gu) wgu[idx] = desc; else wdn[idx] = desc;
    }
}

// ---------------- stage A: gate/up proj + silu, gathered ----------------
// M=128, N=128 merged [w1|w3], BK=64; single-buffer (round-4 structure — the
// measured optimum: dbuf at 66KB LDS cut occupancy and lost 30%). A via
// global_load_lds (bf16 xb), B reg-staged fp32 -> bf16 at LDS write.
__launch_bounds__(256, 4)
__global__ void k_gateup(const ushort* __restrict__ xb, const float* __restrict__ w1,
                         const float* __restrict__ w3, const float* __restrict__ ws1,
                         const float* __restrict__ ws3, const int* __restrict__ counts,
                         const int* __restrict__ offsets, const int* __restrict__ wgu,
                         const int* __restrict__ tok_ids, const float* __restrict__ tok_w,
                         ushort* __restrict__ hact) {
    int desc = wgu[blockIdx.x];
    if (desc < 0) return;
    int e = desc & 31;
    int m0 = ((desc >> 5) & 15) * 128;
    int i0 = ((desc >> 9) & 15) * 64;
    int Me = (e == N_EXP) ? N_TOK : counts[e];
    const float* W1 = (e == N_EXP) ? ws1 : w1 + (size_t)e * I_DIM * H_DIM;
    const float* W3 = (e == N_EXP) ? ws3 : w3 + (size_t)e * I_DIM * H_DIM;
    int base = offsets[e];

    __shared__ ushort As[128][64];
    __shared__ ushort Bs[128][64];   // rows 0-63: w1, rows 64-127: w3
    __shared__ float tws[128];

    int tid = threadIdx.x;
    int wv = tid >> 6, lane = tid & 63;
    int seg = lane & 7, rsub = lane >> 3;
    int gch = (seg ^ rsub) * 8;   // swizzled source chunk (element offset)

    if (tid < 128) {
        int r = m0 + tid;
        tws[tid] = (e == N_EXP) ? 1.f : ((r < Me) ? tok_w[e * N_TOK + r] : 0.f);
    }

    const ushort* aptr[4];
#pragma unroll
    for (int j = 0; j < 4; j++) {
        int gr = m0 + wv * 32 + j * 8 + rsub;
        int tok = (e == N_EXP) ? gr : ((gr < Me) ? tok_ids[e * N_TOK + gr] : 0);
        aptr[j] = xb + (size_t)tok * H_DIM + gch;
    }
    const float* bptrf[4];
#pragma unroll
    for (int j = 0; j < 4; j++) {
        int r = wv * 32 + j * 8 + rsub;  // 0..127
        const float* W = (r < 64) ? (W1 + (size_t)(i0 + r) * H_DIM)
                                  : (W3 + (size_t)(i0 + r - 64) * H_DIM);
        bptrf[j] = W + gch;
    }

    int quad = lane >> 4, lr = lane & 15, rx = lr & 7;
    f32x4 acc[2][8] = {};

    const int NK = H_DIM / 64;
    float4 bv0[4], bv1[4];
#pragma unroll
    for (int j = 0; j < 4; j++) {
        bv0[j] = *(const float4*)(bptrf[j]);
        bv1[j] = *(const float4*)(bptrf[j] + 4);
    }
    for (int k = 0; k < NK; k++) {
        int off = k * 64;
#pragma unroll
        for (int j = 0; j < 4; j++) async_copy16(aptr[j] + off, &As[wv * 32 + j * 8][0]);
#pragma unroll
        for (int j = 0; j < 4; j++) {          // convert + swizzled LDS write
            uint4 p;
            p.x = pack2(bv0[j].x, bv0[j].y);
            p.y = pack2(bv0[j].z, bv0[j].w);
            p.z = pack2(bv1[j].x, bv1[j].y);
            p.w = pack2(bv1[j].z, bv1[j].w);
            *(uint4*)&Bs[wv * 32 + j * 8 + rsub][seg * 8] = p;
        }
        if (k + 1 < NK) {                      // prefetch next K-step B
#pragma unroll
            for (int j = 0; j < 4; j++) {
                bv0[j] = *(const float4*)(bptrf[j] + off + 64);
                bv1[j] = *(const float4*)(bptrf[j] + off + 68);
            }
        }
        __syncthreads();
#pragma unroll
        for (int ks = 0; ks < 2; ks++) {
            int co = ((ks * 4 + quad) ^ rx) * 8;  // swizzled read chunk
            bf16x8 a0 = *(const bf16x8*)&As[wv * 32 + lr][co];
            bf16x8 a1 = *(const bf16x8*)&As[wv * 32 + 16 + lr][co];
#pragma unroll
            for (int ni = 0; ni < 8; ni++) {
                bf16x8 bf = *(const bf16x8*)&Bs[ni * 16 + lr][co];
                acc[0][ni] = __builtin_amdgcn_mfma_f32_16x16x32_bf16(a0, bf, acc[0][ni], 0, 0, 0);
                acc[1][ni] = __builtin_amdgcn_mfma_f32_16x16x32_bf16(a1, bf, acc[1][ni], 0, 0, 0);
            }
        }
        __syncthreads();
    }

    // epilogue: g = acc[.][0..3], u = acc[.][4..7] -> silu(g)*u*tw
#pragma unroll
    for (int mi = 0; mi < 2; mi++) {
#pragma unroll
        for (int ni = 0; ni < 4; ni++) {
            f32x4 g = acc[mi][ni];
            f32x4 u = acc[mi][ni + 4];
#pragma unroll
            for (int rg = 0; rg < 4; rg++) {
                int ml = wv * 32 + mi * 16 + quad * 4 + rg;
                int row = m0 + ml;
                if (row < Me) {
                    float gg = g[rg], uu = u[rg];
                    float act = (gg / (1.f + expf(-gg))) * uu * tws[ml];
                    hact[(size_t)(base + row) * I_DIM + i0 + ni * 16 + lr] = f2bf(act);
                }
            }
        }
    }
}

// ---------------- stage B: down proj + scatter-add ----------------
// M=128 slots, N=128 of H, BK=64 over I=768; same single-buffer structure.
__launch_bounds__(256, 4)
__global__ void k_down(const ushort* __restrict__ hact, const float* __restrict__ w2,
                       const float* __restrict__ ws2, const int* __restrict__ counts,
                       const int* __restrict__ offsets, const int* __restrict__ wdn,
                       const int* __restrict__ tok_ids, float* __restrict__ out) {
    int desc = wdn[blockIdx.x];
    if (desc < 0) return;
    int e = desc & 31;
    int m0 = ((desc >> 5) & 15) * 128;
    int h0 = ((desc >> 9) & 15) * 128;
    int Me = (e == N_EXP) ? N_TOK : counts[e];
    const float* W2 = (e == N_EXP) ? ws2 : w2 + (size_t)e * H_DIM * I_DIM;
    int base = offsets[e];

    __shared__ ushort As[128][64];
    __shared__ ushort Bs[128][64];
    __shared__ int toks[128];

    int tid = threadIdx.x;
    int wv = tid >> 6, lane = tid & 63;
    int seg = lane & 7, rsub = lane >> 3;
    int gch = (seg ^ rsub) * 8;

    if (tid < 128) {
        int r = m0 + tid;
        toks[tid] = (e == N_EXP) ? r : ((r < Me) ? tok_ids[e * N_TOK + r] : 0);
    }

    const ushort* aptr[4];
#pragma unroll
    for (int j = 0; j < 4; j++) {
        int row = wv * 32 + j * 8 + rsub;
        aptr[j] = hact + (size_t)(base + m0 + row) * I_DIM + gch;
    }
    const float* bptrf[4];
#pragma unroll
    for (int j = 0; j < 4; j++) {
        int r = wv * 32 + j * 8 + rsub;
        bptrf[j] = W2 + (size_t)(h0 + r) * I_DIM + gch;
    }

    int quad = lane >> 4, lr = lane & 15, rx = lr & 7;
    f32x4 acc[2][8] = {};

    const int NK = I_DIM / 64;
    float4 bv0[4], bv1[4];
#pragma unroll
    for (int j = 0; j < 4; j++) {
        bv0[j] = *(const float4*)(bptrf[j]);
        bv1[j] = *(const float4*)(bptrf[j] + 4);
    }
    for (int k = 0; k < NK; k++) {
        int off = k * 64;
#pragma unroll
        for (int j = 0; j < 4; j++) async_copy16(aptr[j] + off, &As[wv * 32 + j * 8][0]);
#pragma unroll
        for (int j = 0; j < 4; j++) {
            uint4 p;
            p.x = pack2(bv0[j].x, bv0[j].y);
            p.y = pack2(bv0[j].z, bv0[j].w);
            p.z = pack2(bv1[j].x, bv1[j].y);
            p.w = pack2(bv1[j].z, bv1[j].w);
            *(uint4*)&Bs[wv * 32 + j * 8 + rsub][seg * 8] = p;
        }
        if (k + 1 < NK) {
#pragma unroll
            for (int j = 0; j < 4; j++) {
                bv0[j] = *(const float4*)(bptrf[j] + off + 64);
                bv1[j] = *(const float4*)(bptrf[j] + off + 68);
            }
        }
        __syncthreads();
#pragma unroll
        for (int ks = 0; ks < 2; ks++) {
            int co = ((ks * 4 + quad) ^ rx) * 8;
            bf16x8 a0 = *(const bf16x8*)&As[wv * 32 + lr][co];
            bf16x8 a1 = *(const bf16x8*)&As[wv * 32 + 16 + lr][co];
#pragma unroll
            for (int ni = 0; ni < 8; ni++) {
                bf16x8 bf = *(const bf16x8*)&Bs[ni * 16 + lr][co];
                acc[0][ni] = __builtin_amdgcn_mfma_f32_16x16x32_bf16(a0, bf, acc[0][ni], 0, 0, 0);
                acc[1][ni] = __builtin_amdgcn_mfma_f32_16x16x32_bf16(a1, bf, acc[1][ni], 0, 0, 0);
            }
        }
        __syncthreads();
    }

#pragma unroll
    for (int mi = 0; mi < 2; mi++) {
#pragma unroll
        for (int ni = 0; ni < 8; ni++) {
#pragma unroll
            for (int rg = 0; rg < 4; rg++) {
                int ml = wv * 32 + mi * 16 + quad * 4 + rg;
                int row = m0 + ml;
                if (row < Me) {
                    int tok = toks[ml];
                    atomicAdd(&out[(size_t)tok * H_DIM + h0 + ni * 16 + lr],
                              acc[mi][ni][rg]);
                }
            }
        }
    }
}

extern "C" void kernel_launch(void* const* d_in, const int* in_sizes, int n_in,
                              void* d_out, int out_size, void* d_ws, size_t ws_size,
                              hipStream_t stream) {
    const float* x   = (const float*)d_in[0];
    const float* gw  = (const float*)d_in[1];
    const float* gb  = (const float*)d_in[2];
    const float* w1  = (const float*)d_in[3];
    const float* w2  = (const float*)d_in[4];
    const float* w3  = (const float*)d_in[5];
    const float* ws1 = (const float*)d_in[6];
    const float* ws2 = (const float*)d_in[7];
    const float* ws3 = (const float*)d_in[8];
    float* out = (float*)d_out;

    char* wsb = (char*)d_ws;
    int* counts   = (int*)(wsb + OFF_COUNTS);
    int* offsets  = (int*)(wsb + OFF_OFFSETS);
    int* wgu      = (int*)(wsb + OFF_WGU);
    int* wdn      = (int*)(wsb + OFF_WDN);
    int* tok_ids  = (int*)(wsb + OFF_TOKIDS);
    float* tok_w  = (float*)(wsb + OFF_TOKW);
    ushort* xb    = (ushort*)(wsb + OFF_XB);
    ushort* hact  = (ushort*)(wsb + OFF_HACT);
    float* gwT    = (float*)(wsb + OFF_GWT);

    hipMemsetAsync(wsb, 0, 128, stream);                       // counts
    hipMemsetAsync(d_out, 0, (size_t)out_size * 4, stream);    // zero outputs

    k_gwt<<<N_EXP * H_DIM / 256, 256, 0, stream>>>(gw, gwT);
    k_route<<<N_TOK / 4, 256, 0, stream>>>(x, gwT, gb, counts, tok_ids, tok_w, xb);
    k_scan<<<1, 256, 0, stream>>>(counts, offsets, wgu, wdn);
    k_gateup<<<GU_TAB, 256, 0, stream>>>(xb, w1, w3, ws1, ws3, counts, offsets,
                                         wgu, tok_ids, tok_w, hact);
    k_down<<<DN_TAB, 256, 0, stream>>>(hact, w2, ws2, counts, offsets, wdn,
                                       tok_ids, out);
}

// Round 7
// 364.686 us; speedup vs baseline: 1.0138x; 1.0138x over previous
//
#include <hip/hip_runtime.h>
#include <hip/hip_bf16.h>
#include <math.h>

#define N_TOK 2048
#define H_DIM 1024
#define N_EXP 16
#define I_DIM 768
#define TOPK 4
#define SCALE 2.5f

// XCD-aware work tables: slot F -> XCD F%8 (dispatch round-robin).
// Tiles sharing a weight panel (same expert+N-slice) get the same residue mod 8.
#define GU_SLOTS 256
#define DN_SLOTS 192
#define GU_TAB (8 * GU_SLOTS)   // 2048
#define DN_TAB (8 * DN_SLOTS)   // 1536
#define GU_NY (I_DIM / 64)      // 12
#define DN_NY (H_DIM / 128)     // 8
#define MAX_GRP 832

typedef __attribute__((ext_vector_type(8))) short bf16x8;
typedef __attribute__((ext_vector_type(4))) float f32x4;

// workspace layout (bytes)
#define OFF_COUNTS   0
#define OFF_OFFSETS  128
#define OFF_WGU      256
#define OFF_WDN      (OFF_WGU + GU_TAB*4)
#define OFF_TOKIDS   (OFF_WDN + DN_TAB*4)
#define OFF_TOKW     (OFF_TOKIDS + N_EXP*N_TOK*4)
#define OFF_XB       (OFF_TOKW + N_EXP*N_TOK*4)
#define OFF_HACT     (OFF_XB + (size_t)N_TOK*H_DIM*2)
#define OFF_GWT      (OFF_HACT + (size_t)N_TOK*(TOPK+1)*I_DIM*2)
// total ~20 MB

__device__ __forceinline__ ushort f2bf(float f) {
    union { __hip_bfloat16 h; ushort u; } cv;
    cv.h = __float2bfloat16(f);
    return cv.u;
}
__device__ __forceinline__ unsigned pack2(float lo, float hi) {
    return (unsigned)f2bf(lo) | ((unsigned)f2bf(hi) << 16);
}
__device__ __forceinline__ void async_copy16(const void* g, void* l) {
    __builtin_amdgcn_global_load_lds(
        (const __attribute__((address_space(1))) unsigned int*)g,
        (__attribute__((address_space(3))) unsigned int*)l, 16, 0, 0);
}

// ---------------- gate_w transpose: gwT[k][e] ----------------
__global__ void k_gwt(const float* __restrict__ gw, float* __restrict__ gwT) {
    int i = blockIdx.x * 256 + threadIdx.x;   // 16384 elements
    int k = i >> 4, e = i & 15;
    gwT[i] = gw[e * H_DIM + k];
}

// ---------------- routing: 1 wave/token, lane = (kslice, expert) ----------------
// Also emits xb (bf16 x) from its e==0 lanes — replaces the separate k_xconv.
__launch_bounds__(256)
__global__ void k_route(const float* __restrict__ x, const float* __restrict__ gwT,
                        const float* __restrict__ gb,
                        int* __restrict__ counts, int* __restrict__ tok_ids,
                        float* __restrict__ tok_w, ushort* __restrict__ xb) {
    __shared__ float lgs[4][N_EXP + 1];
    int tid = threadIdx.x;
    int wv = tid >> 6, lane = tid & 63;
    int e = lane & 15, ks = lane >> 4;
    int n = blockIdx.x * 4 + wv;

    const float* xr = x + (size_t)n * H_DIM + ks * 256;
    ushort* xbr = xb + (size_t)n * H_DIM + ks * 256;
    const float* wr = gwT + ks * 256 * N_EXP + e;
    float a0 = 0.f, a1 = 0.f, a2 = 0.f, a3 = 0.f;
#pragma unroll 8
    for (int k = 0; k < 256; k += 4) {
        float4 xv = *(const float4*)(xr + k);
        a0 += xv.x * wr[(k + 0) * N_EXP];
        a1 += xv.y * wr[(k + 1) * N_EXP];
        a2 += xv.z * wr[(k + 2) * N_EXP];
        a3 += xv.w * wr[(k + 3) * N_EXP];
        if (e == 0) {   // bf16 copy of x (each 4-float chunk written once)
            uint2 p;
            p.x = pack2(xv.x, xv.y);
            p.y = pack2(xv.z, xv.w);
            *(uint2*)(xbr + k) = p;
        }
    }
    float acc = (a0 + a1) + (a2 + a3);
    acc += __shfl_xor(acc, 16);
    acc += __shfl_xor(acc, 32);
    if (lane < 16) lgs[wv][lane] = acc;
    __syncthreads();

    if (tid < 4) {
        int n2 = blockIdx.x * 4 + tid;
        float sc[N_EXP], sb[N_EXP];
        for (int ee = 0; ee < N_EXP; ee++) {
            float l = lgs[tid][ee];
            sc[ee] = 1.f / (1.f + expf(-l));
            sb[ee] = sc[ee] + gb[ee];
        }
        float gsc[4];
        for (int g = 0; g < 4; g++) {
            float m1 = -1e30f, m2 = -1e30f;
            for (int j = 0; j < 4; j++) {
                float v = sb[4 * g + j];
                if (v > m1) { m2 = m1; m1 = v; }
                else if (v > m2) m2 = v;
            }
            gsc[g] = m1 + m2;
        }
        int g1 = 0;
        for (int g = 1; g < 4; g++) if (gsc[g] > gsc[g1]) g1 = g;
        int g2 = -1;
        for (int g = 0; g < 4; g++) {
            if (g == g1) continue;
            if (g2 < 0 || gsc[g] > gsc[g2]) g2 = g;
        }
        bool allowed[N_EXP];
        for (int ee = 0; ee < N_EXP; ee++) {
            int grp = ee >> 2;
            allowed[ee] = (grp == g1) || (grp == g2);
        }
        int chosen[TOPK];
        float wsum = 0.f;
        for (int k = 0; k < TOPK; k++) {
            int best = -1;
            for (int ee = 0; ee < N_EXP; ee++) {
                if (!allowed[ee]) continue;
                if (best < 0 || sb[ee] > sb[best]) best = ee;
            }
            chosen[k] = best;
            allowed[best] = false;
            wsum += sc[best];
        }
        float inv = SCALE / (wsum + 1e-20f);
        for (int k = 0; k < TOPK; k++) {
            int ee = chosen[k];
            int p = atomicAdd(&counts[ee], 1);
            tok_ids[ee * N_TOK + p] = n2;
            tok_w[ee * N_TOK + p] = sc[ee] * inv;
        }
    }
}

// ---------------- scan + XCD-aware work tables (fully parallel build) ----------------
// Group = <=4 m-tiles sharing one weight panel (same e, same N-slice).
// Groups enumerated (e, y, mchunk); group id g -> XCD g%8 (within its table).
// Closed-form: gpe[e]=ceil(nmt/4) groups per y -> expert base by 17-elem prefix.
// desc = e | (m << 5) | (y << 9)
__global__ void k_scan(const int* __restrict__ counts, int* __restrict__ offsets,
                       int* __restrict__ wgu, int* __restrict__ wdn) {
    __shared__ int nmt_s[20], gpe_s[20];
    __shared__ int geb[20], deb[20];
    __shared__ int gmeta[MAX_GRP];   // e | m0<<5 | y<<9 | size<<24
    __shared__ int gslot[MAX_GRP];
    __shared__ int ngu_s, ntot_s;
    int tid = threadIdx.x;
    for (int i = tid; i < GU_TAB; i += 256) wgu[i] = -1;
    for (int i = tid; i < DN_TAB; i += 256) wdn[i] = -1;
    if (tid < 17) {
        int c = (tid == 16) ? N_TOK : counts[tid];
        int nm = (c + 127) >> 7;
        nmt_s[tid] = nm;
        gpe_s[tid] = (nm + 3) >> 2;
    }
    __syncthreads();
    if (tid == 0) {
        int off = 0;
        for (int e = 0; e < N_EXP; e++) { offsets[e] = off; off += counts[e]; }
        offsets[N_EXP] = off;   // shared expert base (= 8192)
        int g = 0, d = 0;
        for (int e = 0; e <= N_EXP; e++) {
            geb[e] = g; g += GU_NY * gpe_s[e];
            deb[e] = d; d += DN_NY * gpe_s[e];
        }
        geb[N_EXP + 1] = g; deb[N_EXP + 1] = d;
        ngu_s = g; ntot_s = g + d;
    }
    __syncthreads();
    int ngu = ngu_s, ntot = ntot_s;
    // group metadata, parallel over groups
    for (int g = tid; g < ntot; g += 256) {
        bool gu = g < ngu;
        int r = gu ? g : g - ngu;
        const int* eb = gu ? geb : deb;
        int e = 0;
        while (eb[e + 1] <= r) e++;
        int rem = r - eb[e];
        int gp = gpe_s[e];
        int y = rem / gp, mc = rem - y * gp;
        int m0t = mc * 4;
        int size = nmt_s[e] - m0t; if (size > 4) size = 4;
        gmeta[g] = e | (m0t << 5) | (y << 9) | (size << 24);
    }
    __syncthreads();
    // per-XCD slot prefix: 8 threads for GU, 8 for DN; strided, branch-free
    if (tid < 8) {
        int s = 0;
        for (int g = tid; g < ngu; g += 8) { gslot[g] = s; s += (gmeta[g] >> 24); }
    } else if (tid < 16) {
        int c = tid - 8, s = 0;
        for (int g = ngu + c; g < ntot; g += 8) { gslot[g] = s; s += (gmeta[g] >> 24); }
    }
    __syncthreads();
    // expand groups -> tables (tile k of group g at slot gslot[g]+k on XCD r%8)
    int k = tid & 3;
    for (int g = tid >> 2; g < ntot; g += 64) {
        int p = gmeta[g];
        int size = (p >> 24);
        if (k >= size) continue;
        int desc = (p & 0x1FFF) + (k << 5);
        bool gu = g < ngu;
        int r = gu ? g : g - ngu;
        int idx = (r & 7) + 8 * (gslot[g] + k);
        if (gu) wgu[idx] = desc; else wdn[idx] = desc;
    }
}

// ---------------- stage A: gate/up proj + silu, gathered ----------------
// M=128, N=128 merged [w1|w3], BK=64; single-buffer m97-structure. A via
// global_load_lds (bf16 xb), B reg-staged fp32 -> bf16 at LDS write.
// NOTE: (256,3) is load-bearing — (256,4) clamps to 64 VGPR and spills acc
// (measured twice: WRITE_SIZE 15.7 -> 31+ MB, dur +26 µs). Keep 3.
__launch_bounds__(256, 3)
__global__ void k_gateup(const ushort* __restrict__ xb, const float* __restrict__ w1,
                         const float* __restrict__ w3, const float* __restrict__ ws1,
                         const float* __restrict__ ws3, const int* __restrict__ counts,
                         const int* __restrict__ offsets, const int* __restrict__ wgu,
                         const int* __restrict__ tok_ids, const float* __restrict__ tok_w,
                         ushort* __restrict__ hact) {
    int desc = wgu[blockIdx.x];
    if (desc < 0) return;
    int e = desc & 31;
    int m0 = ((desc >> 5) & 15) * 128;
    int i0 = ((desc >> 9) & 15) * 64;
    int Me = (e == N_EXP) ? N_TOK : counts[e];
    const float* W1 = (e == N_EXP) ? ws1 : w1 + (size_t)e * I_DIM * H_DIM;
    const float* W3 = (e == N_EXP) ? ws3 : w3 + (size_t)e * I_DIM * H_DIM;
    int base = offsets[e];

    __shared__ ushort As[128][64];
    __shared__ ushort Bs[128][64];   // rows 0-63: w1, rows 64-127: w3
    __shared__ float tws[128];

    int tid = threadIdx.x;
    int wv = tid >> 6, lane = tid & 63;
    int seg = lane & 7, rsub = lane >> 3;
    int gch = (seg ^ rsub) * 8;   // swizzled source chunk (element offset)

    if (tid < 128) {
        int r = m0 + tid;
        tws[tid] = (e == N_EXP) ? 1.f : ((r < Me) ? tok_w[e * N_TOK + r] : 0.f);
    }

    const ushort* aptr[4];
#pragma unroll
    for (int j = 0; j < 4; j++) {
        int gr = m0 + wv * 32 + j * 8 + rsub;
        int tok = (e == N_EXP) ? gr : ((gr < Me) ? tok_ids[e * N_TOK + gr] : 0);
        aptr[j] = xb + (size_t)tok * H_DIM + gch;
    }
    const float* bptrf[4];
#pragma unroll
    for (int j = 0; j < 4; j++) {
        int r = wv * 32 + j * 8 + rsub;  // 0..127
        const float* W = (r < 64) ? (W1 + (size_t)(i0 + r) * H_DIM)
                                  : (W3 + (size_t)(i0 + r - 64) * H_DIM);
        bptrf[j] = W + gch;
    }

    int quad = lane >> 4, lr = lane & 15, rx = lr & 7;
    f32x4 acc[2][8] = {};

    const int NK = H_DIM / 64;
    float4 bv0[4], bv1[4];
#pragma unroll
    for (int j = 0; j < 4; j++) {
        bv0[j] = *(const float4*)(bptrf[j]);
        bv1[j] = *(const float4*)(bptrf[j] + 4);
    }
    for (int k = 0; k < NK; k++) {
        int off = k * 64;
#pragma unroll
        for (int j = 0; j < 4; j++) async_copy16(aptr[j] + off, &As[wv * 32 + j * 8][0]);
#pragma unroll
        for (int j = 0; j < 4; j++) {          // convert + swizzled LDS write
            uint4 p;
            p.x = pack2(bv0[j].x, bv0[j].y);
            p.y = pack2(bv0[j].z, bv0[j].w);
            p.z = pack2(bv1[j].x, bv1[j].y);
            p.w = pack2(bv1[j].z, bv1[j].w);
            *(uint4*)&Bs[wv * 32 + j * 8 + rsub][seg * 8] = p;
        }
        if (k + 1 < NK) {                      // prefetch next K-step B
#pragma unroll
            for (int j = 0; j < 4; j++) {
                bv0[j] = *(const float4*)(bptrf[j] + off + 64);
                bv1[j] = *(const float4*)(bptrf[j] + off + 68);
            }
        }
        __syncthreads();
#pragma unroll
        for (int ks = 0; ks < 2; ks++) {
            int co = ((ks * 4 + quad) ^ rx) * 8;  // swizzled read chunk
            bf16x8 a0 = *(const bf16x8*)&As[wv * 32 + lr][co];
            bf16x8 a1 = *(const bf16x8*)&As[wv * 32 + 16 + lr][co];
#pragma unroll
            for (int ni = 0; ni < 8; ni++) {
                bf16x8 bf = *(const bf16x8*)&Bs[ni * 16 + lr][co];
                acc[0][ni] = __builtin_amdgcn_mfma_f32_16x16x32_bf16(a0, bf, acc[0][ni], 0, 0, 0);
                acc[1][ni] = __builtin_amdgcn_mfma_f32_16x16x32_bf16(a1, bf, acc[1][ni], 0, 0, 0);
            }
        }
        __syncthreads();
    }

    // epilogue: g = acc[.][0..3], u = acc[.][4..7] -> silu(g)*u*tw
#pragma unroll
    for (int mi = 0; mi < 2; mi++) {
#pragma unroll
        for (int ni = 0; ni < 4; ni++) {
            f32x4 g = acc[mi][ni];
            f32x4 u = acc[mi][ni + 4];
#pragma unroll
            for (int rg = 0; rg < 4; rg++) {
                int ml = wv * 32 + mi * 16 + quad * 4 + rg;
                int row = m0 + ml;
                if (row < Me) {
                    float gg = g[rg], uu = u[rg];
                    float act = (gg / (1.f + expf(-gg))) * uu * tws[ml];
                    hact[(size_t)(base + row) * I_DIM + i0 + ni * 16 + lr] = f2bf(act);
                }
            }
        }
    }
}

// ---------------- stage B: down proj + scatter-add ----------------
// M=128 slots, N=128 of H, BK=64 over I=768; same single-buffer structure.
__launch_bounds__(256, 3)
__global__ void k_down(const ushort* __restrict__ hact, const float* __restrict__ w2,
                       const float* __restrict__ ws2, const int* __restrict__ counts,
                       const int* __restrict__ offsets, const int* __restrict__ wdn,
                       const int* __restrict__ tok_ids, float* __restrict__ out) {
    int desc = wdn[blockIdx.x];
    if (desc < 0) return;
    int e = desc & 31;
    int m0 = ((desc >> 5) & 15) * 128;
    int h0 = ((desc >> 9) & 15) * 128;
    int Me = (e == N_EXP) ? N_TOK : counts[e];
    const float* W2 = (e == N_EXP) ? ws2 : w2 + (size_t)e * H_DIM * I_DIM;
    int base = offsets[e];

    __shared__ ushort As[128][64];
    __shared__ ushort Bs[128][64];
    __shared__ int toks[128];

    int tid = threadIdx.x;
    int wv = tid >> 6, lane = tid & 63;
    int seg = lane & 7, rsub = lane >> 3;
    int gch = (seg ^ rsub) * 8;

    if (tid < 128) {
        int r = m0 + tid;
        toks[tid] = (e == N_EXP) ? r : ((r < Me) ? tok_ids[e * N_TOK + r] : 0);
    }

    const ushort* aptr[4];
#pragma unroll
    for (int j = 0; j < 4; j++) {
        int row = wv * 32 + j * 8 + rsub;
        aptr[j] = hact + (size_t)(base + m0 + row) * I_DIM + gch;
    }
    const float* bptrf[4];
#pragma unroll
    for (int j = 0; j < 4; j++) {
        int r = wv * 32 + j * 8 + rsub;
        bptrf[j] = W2 + (size_t)(h0 + r) * I_DIM + gch;
    }

    int quad = lane >> 4, lr = lane & 15, rx = lr & 7;
    f32x4 acc[2][8] = {};

    const int NK = I_DIM / 64;
    float4 bv0[4], bv1[4];
#pragma unroll
    for (int j = 0; j < 4; j++) {
        bv0[j] = *(const float4*)(bptrf[j]);
        bv1[j] = *(const float4*)(bptrf[j] + 4);
    }
    for (int k = 0; k < NK; k++) {
        int off = k * 64;
#pragma unroll
        for (int j = 0; j < 4; j++) async_copy16(aptr[j] + off, &As[wv * 32 + j * 8][0]);
#pragma unroll
        for (int j = 0; j < 4; j++) {
            uint4 p;
            p.x = pack2(bv0[j].x, bv0[j].y);
            p.y = pack2(bv0[j].z, bv0[j].w);
            p.z = pack2(bv1[j].x, bv1[j].y);
            p.w = pack2(bv1[j].z, bv1[j].w);
            *(uint4*)&Bs[wv * 32 + j * 8 + rsub][seg * 8] = p;
        }
        if (k + 1 < NK) {
#pragma unroll
            for (int j = 0; j < 4; j++) {
                bv0[j] = *(const float4*)(bptrf[j] + off + 64);
                bv1[j] = *(const float4*)(bptrf[j] + off + 68);
            }
        }
        __syncthreads();
#pragma unroll
        for (int ks = 0; ks < 2; ks++) {
            int co = ((ks * 4 + quad) ^ rx) * 8;
            bf16x8 a0 = *(const bf16x8*)&As[wv * 32 + lr][co];
            bf16x8 a1 = *(const bf16x8*)&As[wv * 32 + 16 + lr][co];
#pragma unroll
            for (int ni = 0; ni < 8; ni++) {
                bf16x8 bf = *(const bf16x8*)&Bs[ni * 16 + lr][co];
                acc[0][ni] = __builtin_amdgcn_mfma_f32_16x16x32_bf16(a0, bf, acc[0][ni], 0, 0, 0);
                acc[1][ni] = __builtin_amdgcn_mfma_f32_16x16x32_bf16(a1, bf, acc[1][ni], 0, 0, 0);
            }
        }
        __syncthreads();
    }

#pragma unroll
    for (int mi = 0; mi < 2; mi++) {
#pragma unroll
        for (int ni = 0; ni < 8; ni++) {
#pragma unroll
            for (int rg = 0; rg < 4; rg++) {
                int ml = wv * 32 + mi * 16 + quad * 4 + rg;
                int row = m0 + ml;
                if (row < Me) {
                    int tok = toks[ml];
                    atomicAdd(&out[(size_t)tok * H_DIM + h0 + ni * 16 + lr],
                              acc[mi][ni][rg]);
                }
            }
        }
    }
}

extern "C" void kernel_launch(void* const* d_in, const int* in_sizes, int n_in,
                              void* d_out, int out_size, void* d_ws, size_t ws_size,
                              hipStream_t stream) {
    const float* x   = (const float*)d_in[0];
    const float* gw  = (const float*)d_in[1];
    const float* gb  = (const float*)d_in[2];
    const float* w1  = (const float*)d_in[3];
    const float* w2  = (const float*)d_in[4];
    const float* w3  = (const float*)d_in[5];
    const float* ws1 = (const float*)d_in[6];
    const float* ws2 = (const float*)d_in[7];
    const float* ws3 = (const float*)d_in[8];
    float* out = (float*)d_out;

    char* wsb = (char*)d_ws;
    int* counts   = (int*)(wsb + OFF_COUNTS);
    int* offsets  = (int*)(wsb + OFF_OFFSETS);
    int* wgu      = (int*)(wsb + OFF_WGU);
    int* wdn      = (int*)(wsb + OFF_WDN);
    int* tok_ids  = (int*)(wsb + OFF_TOKIDS);
    float* tok_w  = (float*)(wsb + OFF_TOKW);
    ushort* xb    = (ushort*)(wsb + OFF_XB);
    ushort* hact  = (ushort*)(wsb + OFF_HACT);
    float* gwT    = (float*)(wsb + OFF_GWT);

    hipMemsetAsync(wsb, 0, 128, stream);                       // counts
    hipMemsetAsync(d_out, 0, (size_t)out_size * 4, stream);    // zero outputs

    k_gwt<<<N_EXP * H_DIM / 256, 256, 0, stream>>>(gw, gwT);
    k_route<<<N_TOK / 4, 256, 0, stream>>>(x, gwT, gb, counts, tok_ids, tok_w, xb);
    k_scan<<<1, 256, 0, stream>>>(counts, offsets, wgu, wdn);
    k_gateup<<<GU_TAB, 256, 0, stream>>>(xb, w1, w3, ws1, ws3, counts, offsets,
                                         wgu, tok_ids, tok_w, hact);
    k_down<<<DN_TAB, 256, 0, stream>>>(hact, w2, ws2, counts, offsets, wdn,
                                       tok_ids, out);
}

// Round 8
// 351.302 us; speedup vs baseline: 1.0524x; 1.0381x over previous
//
#include <hip/hip_runtime.h>
#include <hip/hip_bf16.h>
#include <math.h>

#define N_TOK 2048
#define H_DIM 1024
#define N_EXP 16
#define I_DIM 768
#define TOPK 4
#define SCALE 2.5f

// XCD-aware work tables: slot F -> XCD F%8 (dispatch round-robin).
// Tiles sharing a weight panel (same expert+N-slice) get the same residue mod 8.
#define GU_SLOTS 256
#define DN_SLOTS 192
#define GU_TAB (8 * GU_SLOTS)   // 2048
#define DN_TAB (8 * DN_SLOTS)   // 1536
#define GU_NY (I_DIM / 64)      // 12
#define DN_NY (H_DIM / 128)     // 8
#define MAX_GRP 832

typedef __attribute__((ext_vector_type(8))) short bf16x8;
typedef __attribute__((ext_vector_type(4))) float f32x4;

// workspace layout (bytes)
#define OFF_COUNTS   0
#define OFF_OFFSETS  128
#define OFF_WGU      256
#define OFF_WDN      (OFF_WGU + GU_TAB*4)
#define OFF_TOKIDS   (OFF_WDN + DN_TAB*4)
#define OFF_TOKW     (OFF_TOKIDS + N_EXP*N_TOK*4)
#define OFF_INV      (OFF_TOKW + N_EXP*N_TOK*4)
#define OFF_XB       (OFF_INV + N_TOK*TOPK*4)
#define OFF_HACT     (OFF_XB + (size_t)N_TOK*H_DIM*2)
#define OFF_GWT      (OFF_HACT + (size_t)N_TOK*(TOPK+1)*I_DIM*2)
#define OFF_YTMP     (OFF_GWT + N_EXP*H_DIM*4)
// total ~62 MB (ytmp = 10240*1024*4 = 41.9 MB)

__device__ __forceinline__ ushort f2bf(float f) {
    union { __hip_bfloat16 h; ushort u; } cv;
    cv.h = __float2bfloat16(f);
    return cv.u;
}
__device__ __forceinline__ unsigned pack2(float lo, float hi) {
    return (unsigned)f2bf(lo) | ((unsigned)f2bf(hi) << 16);
}
__device__ __forceinline__ void async_copy16(const void* g, void* l) {
    __builtin_amdgcn_global_load_lds(
        (const __attribute__((address_space(1))) unsigned int*)g,
        (__attribute__((address_space(3))) unsigned int*)l, 16, 0, 0);
}

// ---------------- gate_w transpose: gwT[k][e] ----------------
__global__ void k_gwt(const float* __restrict__ gw, float* __restrict__ gwT) {
    int i = blockIdx.x * 256 + threadIdx.x;   // 16384 elements
    int k = i >> 4, e = i & 15;
    gwT[i] = gw[e * H_DIM + k];
}

// ---------------- routing: 1 wave/token, lane = (kslice, expert) ----------------
// Also emits xb (bf16 x) from its e==0 lanes, and inv[t][k] = (e<<16)|p for the
// atomic-free down-proj reduce.
__launch_bounds__(256)
__global__ void k_route(const float* __restrict__ x, const float* __restrict__ gwT,
                        const float* __restrict__ gb,
                        int* __restrict__ counts, int* __restrict__ tok_ids,
                        float* __restrict__ tok_w, ushort* __restrict__ xb,
                        int* __restrict__ inv) {
    __shared__ float lgs[4][N_EXP + 1];
    int tid = threadIdx.x;
    int wv = tid >> 6, lane = tid & 63;
    int e = lane & 15, ks = lane >> 4;
    int n = blockIdx.x * 4 + wv;

    const float* xr = x + (size_t)n * H_DIM + ks * 256;
    ushort* xbr = xb + (size_t)n * H_DIM + ks * 256;
    const float* wr = gwT + ks * 256 * N_EXP + e;
    float a0 = 0.f, a1 = 0.f, a2 = 0.f, a3 = 0.f;
#pragma unroll 8
    for (int k = 0; k < 256; k += 4) {
        float4 xv = *(const float4*)(xr + k);
        a0 += xv.x * wr[(k + 0) * N_EXP];
        a1 += xv.y * wr[(k + 1) * N_EXP];
        a2 += xv.z * wr[(k + 2) * N_EXP];
        a3 += xv.w * wr[(k + 3) * N_EXP];
        if (e == 0) {   // bf16 copy of x (each 4-float chunk written once)
            uint2 p;
            p.x = pack2(xv.x, xv.y);
            p.y = pack2(xv.z, xv.w);
            *(uint2*)(xbr + k) = p;
        }
    }
    float acc = (a0 + a1) + (a2 + a3);
    acc += __shfl_xor(acc, 16);
    acc += __shfl_xor(acc, 32);
    if (lane < 16) lgs[wv][lane] = acc;
    __syncthreads();

    if (tid < 4) {
        int n2 = blockIdx.x * 4 + tid;
        float sc[N_EXP], sb[N_EXP];
        for (int ee = 0; ee < N_EXP; ee++) {
            float l = lgs[tid][ee];
            sc[ee] = 1.f / (1.f + expf(-l));
            sb[ee] = sc[ee] + gb[ee];
        }
        float gsc[4];
        for (int g = 0; g < 4; g++) {
            float m1 = -1e30f, m2 = -1e30f;
            for (int j = 0; j < 4; j++) {
                float v = sb[4 * g + j];
                if (v > m1) { m2 = m1; m1 = v; }
                else if (v > m2) m2 = v;
            }
            gsc[g] = m1 + m2;
        }
        int g1 = 0;
        for (int g = 1; g < 4; g++) if (gsc[g] > gsc[g1]) g1 = g;
        int g2 = -1;
        for (int g = 0; g < 4; g++) {
            if (g == g1) continue;
            if (g2 < 0 || gsc[g] > gsc[g2]) g2 = g;
        }
        bool allowed[N_EXP];
        for (int ee = 0; ee < N_EXP; ee++) {
            int grp = ee >> 2;
            allowed[ee] = (grp == g1) || (grp == g2);
        }
        int chosen[TOPK];
        float wsum = 0.f;
        for (int k = 0; k < TOPK; k++) {
            int best = -1;
            for (int ee = 0; ee < N_EXP; ee++) {
                if (!allowed[ee]) continue;
                if (best < 0 || sb[ee] > sb[best]) best = ee;
            }
            chosen[k] = best;
            allowed[best] = false;
            wsum += sc[best];
        }
        float inv_w = SCALE / (wsum + 1e-20f);
        for (int k = 0; k < TOPK; k++) {
            int ee = chosen[k];
            int p = atomicAdd(&counts[ee], 1);
            tok_ids[ee * N_TOK + p] = n2;
            tok_w[ee * N_TOK + p] = sc[ee] * inv_w;
            inv[n2 * TOPK + k] = (ee << 16) | p;
        }
    }
}

// ---------------- scan + XCD-aware work tables (fully parallel build) ----------------
// Group = <=4 m-tiles sharing one weight panel (same e, same N-slice).
// Groups enumerated (e, y, mchunk); group id g -> XCD g%8 (within its table).
// desc = e | (m << 5) | (y << 9)
__global__ void k_scan(const int* __restrict__ counts, int* __restrict__ offsets,
                       int* __restrict__ wgu, int* __restrict__ wdn) {
    __shared__ int nmt_s[20], gpe_s[20];
    __shared__ int geb[20], deb[20];
    __shared__ int gmeta[MAX_GRP];   // e | m0<<5 | y<<9 | size<<24
    __shared__ int gslot[MAX_GRP];
    __shared__ int ngu_s, ntot_s;
    int tid = threadIdx.x;
    for (int i = tid; i < GU_TAB; i += 256) wgu[i] = -1;
    for (int i = tid; i < DN_TAB; i += 256) wdn[i] = -1;
    if (tid < 17) {
        int c = (tid == 16) ? N_TOK : counts[tid];
        int nm = (c + 127) >> 7;
        nmt_s[tid] = nm;
        gpe_s[tid] = (nm + 3) >> 2;
    }
    __syncthreads();
    if (tid == 0) {
        int off = 0;
        for (int e = 0; e < N_EXP; e++) { offsets[e] = off; off += counts[e]; }
        offsets[N_EXP] = off;   // shared expert base (= 8192)
        int g = 0, d = 0;
        for (int e = 0; e <= N_EXP; e++) {
            geb[e] = g; g += GU_NY * gpe_s[e];
            deb[e] = d; d += DN_NY * gpe_s[e];
        }
        geb[N_EXP + 1] = g; deb[N_EXP + 1] = d;
        ngu_s = g; ntot_s = g + d;
    }
    __syncthreads();
    int ngu = ngu_s, ntot = ntot_s;
    for (int g = tid; g < ntot; g += 256) {
        bool gu = g < ngu;
        int r = gu ? g : g - ngu;
        const int* eb = gu ? geb : deb;
        int e = 0;
        while (eb[e + 1] <= r) e++;
        int rem = r - eb[e];
        int gp = gpe_s[e];
        int y = rem / gp, mc = rem - y * gp;
        int m0t = mc * 4;
        int size = nmt_s[e] - m0t; if (size > 4) size = 4;
        gmeta[g] = e | (m0t << 5) | (y << 9) | (size << 24);
    }
    __syncthreads();
    if (tid < 8) {
        int s = 0;
        for (int g = tid; g < ngu; g += 8) { gslot[g] = s; s += (gmeta[g] >> 24); }
    } else if (tid < 16) {
        int c = tid - 8, s = 0;
        for (int g = ngu + c; g < ntot; g += 8) { gslot[g] = s; s += (gmeta[g] >> 24); }
    }
    __syncthreads();
    int k = tid & 3;
    for (int g = tid >> 2; g < ntot; g += 64) {
        int p = gmeta[g];
        int size = (p >> 24);
        if (k >= size) continue;
        int desc = (p & 0x1FFF) + (k << 5);
        bool gu = g < ngu;
        int r = gu ? g : g - ngu;
        int idx = (r & 7) + 8 * (gslot[g] + k);
        if (gu) wgu[idx] = desc; else wdn[idx] = desc;
    }
}

// ---------------- stage A: gate/up proj + silu, gathered ----------------
// M=128, N=128 merged [w1|w3], BK=64; single-buffer m97-structure. A via
// global_load_lds (bf16 xb), B reg-staged fp32 -> bf16 at LDS write.
// NOTE: (256,3) is load-bearing — (256,4) clamps to 64 VGPR and spills acc
// (measured twice: WRITE_SIZE 15.7 -> 31+ MB, dur +26 µs). Keep 3.
__launch_bounds__(256, 3)
__global__ void k_gateup(const ushort* __restrict__ xb, const float* __restrict__ w1,
                         const float* __restrict__ w3, const float* __restrict__ ws1,
                         const float* __restrict__ ws3, const int* __restrict__ counts,
                         const int* __restrict__ offsets, const int* __restrict__ wgu,
                         const int* __restrict__ tok_ids, const float* __restrict__ tok_w,
                         ushort* __restrict__ hact) {
    int desc = wgu[blockIdx.x];
    if (desc < 0) return;
    int e = desc & 31;
    int m0 = ((desc >> 5) & 15) * 128;
    int i0 = ((desc >> 9) & 15) * 64;
    int Me = (e == N_EXP) ? N_TOK : counts[e];
    const float* W1 = (e == N_EXP) ? ws1 : w1 + (size_t)e * I_DIM * H_DIM;
    const float* W3 = (e == N_EXP) ? ws3 : w3 + (size_t)e * I_DIM * H_DIM;
    int base = offsets[e];

    __shared__ ushort As[128][64];
    __shared__ ushort Bs[128][64];   // rows 0-63: w1, rows 64-127: w3
    __shared__ float tws[128];

    int tid = threadIdx.x;
    int wv = tid >> 6, lane = tid & 63;
    int seg = lane & 7, rsub = lane >> 3;
    int gch = (seg ^ rsub) * 8;   // swizzled source chunk (element offset)

    if (tid < 128) {
        int r = m0 + tid;
        tws[tid] = (e == N_EXP) ? 1.f : ((r < Me) ? tok_w[e * N_TOK + r] : 0.f);
    }

    const ushort* aptr[4];
#pragma unroll
    for (int j = 0; j < 4; j++) {
        int gr = m0 + wv * 32 + j * 8 + rsub;
        int tok = (e == N_EXP) ? gr : ((gr < Me) ? tok_ids[e * N_TOK + gr] : 0);
        aptr[j] = xb + (size_t)tok * H_DIM + gch;
    }
    const float* bptrf[4];
#pragma unroll
    for (int j = 0; j < 4; j++) {
        int r = wv * 32 + j * 8 + rsub;  // 0..127
        const float* W = (r < 64) ? (W1 + (size_t)(i0 + r) * H_DIM)
                                  : (W3 + (size_t)(i0 + r - 64) * H_DIM);
        bptrf[j] = W + gch;
    }

    int quad = lane >> 4, lr = lane & 15, rx = lr & 7;
    f32x4 acc[2][8] = {};

    const int NK = H_DIM / 64;
    float4 bv0[4], bv1[4];
#pragma unroll
    for (int j = 0; j < 4; j++) {
        bv0[j] = *(const float4*)(bptrf[j]);
        bv1[j] = *(const float4*)(bptrf[j] + 4);
    }
    for (int k = 0; k < NK; k++) {
        int off = k * 64;
#pragma unroll
        for (int j = 0; j < 4; j++) async_copy16(aptr[j] + off, &As[wv * 32 + j * 8][0]);
#pragma unroll
        for (int j = 0; j < 4; j++) {          // convert + swizzled LDS write
            uint4 p;
            p.x = pack2(bv0[j].x, bv0[j].y);
            p.y = pack2(bv0[j].z, bv0[j].w);
            p.z = pack2(bv1[j].x, bv1[j].y);
            p.w = pack2(bv1[j].z, bv1[j].w);
            *(uint4*)&Bs[wv * 32 + j * 8 + rsub][seg * 8] = p;
        }
        if (k + 1 < NK) {                      // prefetch next K-step B
#pragma unroll
            for (int j = 0; j < 4; j++) {
                bv0[j] = *(const float4*)(bptrf[j] + off + 64);
                bv1[j] = *(const float4*)(bptrf[j] + off + 68);
            }
        }
        __syncthreads();
#pragma unroll
        for (int ks = 0; ks < 2; ks++) {
            int co = ((ks * 4 + quad) ^ rx) * 8;  // swizzled read chunk
            bf16x8 a0 = *(const bf16x8*)&As[wv * 32 + lr][co];
            bf16x8 a1 = *(const bf16x8*)&As[wv * 32 + 16 + lr][co];
#pragma unroll
            for (int ni = 0; ni < 8; ni++) {
                bf16x8 bf = *(const bf16x8*)&Bs[ni * 16 + lr][co];
                acc[0][ni] = __builtin_amdgcn_mfma_f32_16x16x32_bf16(a0, bf, acc[0][ni], 0, 0, 0);
                acc[1][ni] = __builtin_amdgcn_mfma_f32_16x16x32_bf16(a1, bf, acc[1][ni], 0, 0, 0);
            }
        }
        __syncthreads();
    }

    // epilogue: g = acc[.][0..3], u = acc[.][4..7] -> silu(g)*u*tw
#pragma unroll
    for (int mi = 0; mi < 2; mi++) {
#pragma unroll
        for (int ni = 0; ni < 4; ni++) {
            f32x4 g = acc[mi][ni];
            f32x4 u = acc[mi][ni + 4];
#pragma unroll
            for (int rg = 0; rg < 4; rg++) {
                int ml = wv * 32 + mi * 16 + quad * 4 + rg;
                int row = m0 + ml;
                if (row < Me) {
                    float gg = g[rg], uu = u[rg];
                    float act = (gg / (1.f + expf(-gg))) * uu * tws[ml];
                    hact[(size_t)(base + row) * I_DIM + i0 + ni * 16 + lr] = f2bf(act);
                }
            }
        }
    }
}

// ---------------- stage B: down proj -> slot-major ytmp (atomic-free) ----------------
// M=128 slots, N=128 of H, BK=64 over I=768; single-buffer structure.
// Slots are disjoint rows of ytmp -> plain coalesced stores, no atomics,
// no toks staging, no tok_ids dependency.
__launch_bounds__(256, 3)
__global__ void k_down(const ushort* __restrict__ hact, const float* __restrict__ w2,
                       const float* __restrict__ ws2, const int* __restrict__ counts,
                       const int* __restrict__ offsets, const int* __restrict__ wdn,
                       float* __restrict__ ytmp) {
    int desc = wdn[blockIdx.x];
    if (desc < 0) return;
    int e = desc & 31;
    int m0 = ((desc >> 5) & 15) * 128;
    int h0 = ((desc >> 9) & 15) * 128;
    int Me = (e == N_EXP) ? N_TOK : counts[e];
    const float* W2 = (e == N_EXP) ? ws2 : w2 + (size_t)e * H_DIM * I_DIM;
    int base = offsets[e];

    __shared__ ushort As[128][64];
    __shared__ ushort Bs[128][64];

    int tid = threadIdx.x;
    int wv = tid >> 6, lane = tid & 63;
    int seg = lane & 7, rsub = lane >> 3;
    int gch = (seg ^ rsub) * 8;

    const ushort* aptr[4];
#pragma unroll
    for (int j = 0; j < 4; j++) {
        int row = wv * 32 + j * 8 + rsub;
        aptr[j] = hact + (size_t)(base + m0 + row) * I_DIM + gch;
    }
    const float* bptrf[4];
#pragma unroll
    for (int j = 0; j < 4; j++) {
        int r = wv * 32 + j * 8 + rsub;
        bptrf[j] = W2 + (size_t)(h0 + r) * I_DIM + gch;
    }

    int quad = lane >> 4, lr = lane & 15, rx = lr & 7;
    f32x4 acc[2][8] = {};

    const int NK = I_DIM / 64;
    float4 bv0[4], bv1[4];
#pragma unroll
    for (int j = 0; j < 4; j++) {
        bv0[j] = *(const float4*)(bptrf[j]);
        bv1[j] = *(const float4*)(bptrf[j] + 4);
    }
    for (int k = 0; k < NK; k++) {
        int off = k * 64;
#pragma unroll
        for (int j = 0; j < 4; j++) async_copy16(aptr[j] + off, &As[wv * 32 + j * 8][0]);
#pragma unroll
        for (int j = 0; j < 4; j++) {
            uint4 p;
            p.x = pack2(bv0[j].x, bv0[j].y);
            p.y = pack2(bv0[j].z, bv0[j].w);
            p.z = pack2(bv1[j].x, bv1[j].y);
            p.w = pack2(bv1[j].z, bv1[j].w);
            *(uint4*)&Bs[wv * 32 + j * 8 + rsub][seg * 8] = p;
        }
        if (k + 1 < NK) {
#pragma unroll
            for (int j = 0; j < 4; j++) {
                bv0[j] = *(const float4*)(bptrf[j] + off + 64);
                bv1[j] = *(const float4*)(bptrf[j] + off + 68);
            }
        }
        __syncthreads();
#pragma unroll
        for (int ks = 0; ks < 2; ks++) {
            int co = ((ks * 4 + quad) ^ rx) * 8;
            bf16x8 a0 = *(const bf16x8*)&As[wv * 32 + lr][co];
            bf16x8 a1 = *(const bf16x8*)&As[wv * 32 + 16 + lr][co];
#pragma unroll
            for (int ni = 0; ni < 8; ni++) {
                bf16x8 bf = *(const bf16x8*)&Bs[ni * 16 + lr][co];
                acc[0][ni] = __builtin_amdgcn_mfma_f32_16x16x32_bf16(a0, bf, acc[0][ni], 0, 0, 0);
                acc[1][ni] = __builtin_amdgcn_mfma_f32_16x16x32_bf16(a1, bf, acc[1][ni], 0, 0, 0);
            }
        }
        __syncthreads();
    }

#pragma unroll
    for (int mi = 0; mi < 2; mi++) {
#pragma unroll
        for (int ni = 0; ni < 8; ni++) {
#pragma unroll
            for (int rg = 0; rg < 4; rg++) {
                int ml = wv * 32 + mi * 16 + quad * 4 + rg;
                int row = m0 + ml;
                if (row < Me) {
                    ytmp[(size_t)(base + row) * H_DIM + h0 + ni * 16 + lr] =
                        acc[mi][ni][rg];
                }
            }
        }
    }
}

// ---------------- final: per-token gather of 4 routed slots + shared slot ----------------
// Replaces the out memset + atomics. 40 MB read + 8 MB write, HBM-bound.
__launch_bounds__(256)
__global__ void k_reduce(const float* __restrict__ ytmp, const int* __restrict__ inv,
                         const int* __restrict__ offsets, float* __restrict__ out) {
    int t = blockIdx.x, tid = threadIdx.x;
    const float4* yt = (const float4*)ytmp;
    float4 s = yt[(size_t)(offsets[N_EXP] + t) * (H_DIM / 4) + tid];   // shared expert
#pragma unroll
    for (int k = 0; k < TOPK; k++) {
        int v = inv[t * TOPK + k];
        int slot = offsets[v >> 16] + (v & 0xFFFF);
        float4 a = yt[(size_t)slot * (H_DIM / 4) + tid];
        s.x += a.x; s.y += a.y; s.z += a.z; s.w += a.w;
    }
    ((float4*)out)[(size_t)t * (H_DIM / 4) + tid] = s;
}

extern "C" void kernel_launch(void* const* d_in, const int* in_sizes, int n_in,
                              void* d_out, int out_size, void* d_ws, size_t ws_size,
                              hipStream_t stream) {
    const float* x   = (const float*)d_in[0];
    const float* gw  = (const float*)d_in[1];
    const float* gb  = (const float*)d_in[2];
    const float* w1  = (const float*)d_in[3];
    const float* w2  = (const float*)d_in[4];
    const float* w3  = (const float*)d_in[5];
    const float* ws1 = (const float*)d_in[6];
    const float* ws2 = (const float*)d_in[7];
    const float* ws3 = (const float*)d_in[8];
    float* out = (float*)d_out;

    char* wsb = (char*)d_ws;
    int* counts   = (int*)(wsb + OFF_COUNTS);
    int* offsets  = (int*)(wsb + OFF_OFFSETS);
    int* wgu      = (int*)(wsb + OFF_WGU);
    int* wdn      = (int*)(wsb + OFF_WDN);
    int* tok_ids  = (int*)(wsb + OFF_TOKIDS);
    float* tok_w  = (float*)(wsb + OFF_TOKW);
    int* inv      = (int*)(wsb + OFF_INV);
    ushort* xb    = (ushort*)(wsb + OFF_XB);
    ushort* hact  = (ushort*)(wsb + OFF_HACT);
    float* gwT    = (float*)(wsb + OFF_GWT);
    float* ytmp   = (float*)(wsb + OFF_YTMP);

    hipMemsetAsync(wsb, 0, 128, stream);                       // counts

    k_gwt<<<N_EXP * H_DIM / 256, 256, 0, stream>>>(gw, gwT);
    k_route<<<N_TOK / 4, 256, 0, stream>>>(x, gwT, gb, counts, tok_ids, tok_w, xb, inv);
    k_scan<<<1, 256, 0, stream>>>(counts, offsets, wgu, wdn);
    k_gateup<<<GU_TAB, 256, 0, stream>>>(xb, w1, w3, ws1, ws3, counts, offsets,
                                         wgu, tok_ids, tok_w, hact);
    k_down<<<DN_TAB, 256, 0, stream>>>(hact, w2, ws2, counts, offsets, wdn, ytmp);
    k_reduce<<<N_TOK, 256, 0, stream>>>(ytmp, inv, offsets, out);
}